// Round 4
// baseline (247.550 us; speedup 1.0000x reference)
//
#include <hip/hip_runtime.h>

// Involution via bf16 MFMA tap-GEMM, operand-swapped (D[t][px]) so the
// normalization + 7x7 involution run fully in registers (no ker LDS round
// trip, no in-loop barriers). hv GEMV is k-split 4x for latency hiding.

#define C_    256
#define HID_  64
#define KS_   7
#define KK_   49
#define G_    256
#define H_    64
#define W_    64
#define HW_   4096
#define BN_EPS 1e-5f

typedef __attribute__((ext_vector_type(8))) short bf16x8;
typedef __attribute__((ext_vector_type(4))) float f32x4;

__device__ __forceinline__ ushort f2bf(float f) {
    unsigned u = __float_as_uint(f);
    return (ushort)((u + 0x7fffu + ((u >> 16) & 1u)) >> 16);   // RNE
}

// ---------------------------------------------------------------- prep ----
// blocks 0..255: kwb[g][t][k] bf16, t padded 49->64 with zeros.
// block 256: rwT[k][o] = reduce_w[o][k]*bn_inv[o]; betp[o].
// block 257: kbp[g][t] = bias padded 49->64 with zeros.
__global__ __launch_bounds__(256) void prep_kernel(
    const float* __restrict__ kw, const float* __restrict__ kb,
    const float* __restrict__ reduce_w,
    const float* __restrict__ bn_gamma, const float* __restrict__ bn_beta,
    const float* __restrict__ bn_mean, const float* __restrict__ bn_var,
    ushort* __restrict__ kwb, float* __restrict__ rwT, float* __restrict__ betp,
    float* __restrict__ kbp)
{
    if (blockIdx.x < 256) {
        int idx  = blockIdx.x * 256 + threadIdx.x;
        int base = idx * 16;
        int g    = base >> 12;
        int rem  = base & 4095;
        int t    = rem >> 6;
        int k0   = rem & 63;
        union { ushort s[16]; uint4 v[2]; } u;
        if (t < KK_) {
            const float* src = kw + ((size_t)(g * KK_ + t)) * HID_ + k0;
            #pragma unroll
            for (int i = 0; i < 16; ++i) u.s[i] = f2bf(src[i]);
        } else {
            #pragma unroll
            for (int i = 0; i < 16; ++i) u.s[i] = 0;
        }
        uint4* dst = (uint4*)(kwb + base);
        dst[0] = u.v[0];
        dst[1] = u.v[1];
    } else if (blockIdx.x == 256) {
        int k = threadIdx.x;
        #pragma unroll 1
        for (int o = 0; o < HID_; ++o) {
            float inv = bn_gamma[o] * rsqrtf(bn_var[o] + BN_EPS);
            rwT[k * HID_ + o] = reduce_w[o * C_ + k] * inv;
        }
        if (k < HID_) {
            float inv = bn_gamma[k] * rsqrtf(bn_var[k] + BN_EPS);
            betp[k] = bn_beta[k] - bn_mean[k] * inv;
        }
    } else {
        for (int i = threadIdx.x; i < G_ * 64; i += 256) {
            int g = i >> 6, t = i & 63;
            kbp[i] = (t < KK_) ? kb[g * KK_ + t] : 0.f;
        }
    }
}

// ----------------------------------------------------------------- hv1 ----
// partial GEMV over one k-quarter: hvp[kq*64+o][p] = sum_{k in quarter}.
__global__ __launch_bounds__(256) void hv1_kernel(
    const float* __restrict__ x, const float* __restrict__ rwT,
    float* __restrict__ hvp, int npx)
{
    const int lane = threadIdx.x & 63;
    const int wq   = __builtin_amdgcn_readfirstlane(threadIdx.x >> 6);
    const int kq   = blockIdx.y;
    const int p    = blockIdx.x * 64 + lane;
    const int b    = p >> 12;
    const int hw   = p & 4095;

    float acc[16];
    #pragma unroll
    for (int j = 0; j < 16; ++j) acc[j] = 0.f;

    const float* xp = x + ((size_t)b * C_ + kq * 64) * HW_ + hw;
    const float* rw = rwT + (kq * 64) * HID_ + wq * 16;
    #pragma unroll 8
    for (int kk = 0; kk < 64; ++kk) {
        float xk = xp[(size_t)kk * HW_];
        #pragma unroll
        for (int j = 0; j < 16; ++j) acc[j] = fmaf(xk, rw[kk * HID_ + j], acc[j]);
    }
    float* dst = hvp + ((size_t)(kq * 64 + wq * 16)) * npx + p;
    #pragma unroll
    for (int j = 0; j < 16; ++j) dst[(size_t)j * npx] = acc[j];
}

// ----------------------------------------------------------------- hv2 ----
// hv[p][o] = bf16(relu(sum_kq hvp + betp[o]))
__global__ __launch_bounds__(256) void hv2_kernel(
    const float* __restrict__ hvp, const float* __restrict__ betp,
    ushort* __restrict__ hv, int npx)
{
    const int p  = blockIdx.x * 256 + threadIdx.x;
    const int o0 = blockIdx.y * 4;
    ushort s[4];
    #pragma unroll
    for (int j = 0; j < 4; ++j) {
        float v = 0.f;
        #pragma unroll
        for (int kq = 0; kq < 4; ++kq)
            v += hvp[(size_t)(kq * 64 + o0 + j) * npx + p];
        s[j] = f2bf(fmaxf(v + betp[o0 + j], 0.f));
    }
    uint2 w;
    w.x = (uint)s[0] | ((uint)s[1] << 16);
    w.y = (uint)s[2] | ((uint)s[3] << 16);
    *(uint2*)(hv + (size_t)p * HID_ + o0) = w;
}

// ---------------------------------------------------------------- main ----
// Block: one image row (64 px) x 16 groups, 4 waves x 4 iters.
// MFMA: D[t][px] = kw(t x k) . hv^T(k x px); lane holds t=(l4*4+r)+16tm,
// px=l15+16pn. Norm + involution fully in registers; x tile per wave in LDS.
__global__ __launch_bounds__(256) void invol_main(
    const float* __restrict__ x, const ushort* __restrict__ hv,
    const ushort* __restrict__ kwb, const float* __restrict__ kbp,
    float* __restrict__ out)
{
    __shared__ ushort hv_s[64 * HID_];     // 8 KB, XOR-swizzled rows
    __shared__ float  x_s[4][KS_][72];     // 8064 B, per-wave 7x70 padded tile

    const int tid  = threadIdx.x;
    const int lane = tid & 63;
    const int wave = __builtin_amdgcn_readfirstlane(tid >> 6);
    const int b = blockIdx.x >> 6;
    const int y = blockIdx.x & 63;
    const int rowpix = (b << 12) + (y << 6);

    {   // stage hv row tile (swizzled: byte ^= (row&7)<<4)
        int px = tid >> 2, c = tid & 3;
        const uint4* src = (const uint4*)(hv + (size_t)(rowpix + px) * HID_ + c * 16);
        int d0 = (px * 128 + c * 32) ^ ((px & 7) << 4);
        int d1 = (px * 128 + c * 32 + 16) ^ ((px & 7) << 4);
        *(uint4*)((char*)hv_s + d0) = src[0];
        *(uint4*)((char*)hv_s + d1) = src[1];
    }
    __syncthreads();

    const int l15 = lane & 15;
    const int l4  = lane >> 4;

    // per-lane tap offsets into x_s row-space: t = tm*16 + l4*4 + r
    int offs[3][4];
    #pragma unroll
    for (int tm = 0; tm < 3; ++tm)
        #pragma unroll
        for (int r = 0; r < 4; ++r) {
            int t = tm * 16 + l4 * 4 + r;
            int i = (t * 147) >> 10;       // t/7 for t<64
            int j = t - i * 7;
            offs[tm][r] = i * 72 + j;
        }

    for (int iter = 0; iter < 4; ++iter) {
        const int g = blockIdx.y * 16 + iter * 4 + wave;

        // A frags (kw): lane holds kw[t=tm*16+l15][k=ks*32+l4*8+j]
        bf16x8 ka[2][4];
        const char* kwg = (const char*)kwb + (size_t)g * 8192;
        #pragma unroll
        for (int ks = 0; ks < 2; ++ks)
            #pragma unroll
            for (int tm = 0; tm < 4; ++tm) {
                int byte = (tm * 16 + l15) * 128 + ks * 64 + l4 * 16;
                ka[ks][tm] = *(const bf16x8*)(kwg + byte);
            }
        // B frags (hv): lane holds hv[px=pn*16+l15][k=ks*32+l4*8+j]
        bf16x8 hb[2][4];
        #pragma unroll
        for (int ks = 0; ks < 2; ++ks)
            #pragma unroll
            for (int pn = 0; pn < 4; ++pn) {
                int row  = pn * 16 + l15;
                int byte = (row * 128 + ks * 64 + l4 * 16) ^ ((row & 7) << 4);
                hb[ks][pn] = *(const bf16x8*)((const char*)hv_s + byte);
            }

        // stage x 7x70 tile for this wave's group (wave-private, no barrier)
        const float* xg = x + ((size_t)(b * G_ + g)) * HW_;
        #pragma unroll
        for (int i = 0; i < KS_; ++i) {
            int yy = y + i - 3;
            bool rv = (unsigned)yy < (unsigned)H_;
            int yc = rv ? yy : 0;
            int c0 = lane - 3;
            float v0 = xg[yc * W_ + (c0 >= 0 ? c0 : 0)];
            x_s[wave][i][lane] = (rv && c0 >= 0) ? v0 : 0.f;
            if (lane < 6) {
                int c1 = 61 + lane;
                float v1 = xg[yc * W_ + (c1 < W_ ? c1 : W_ - 1)];
                x_s[wave][i][64 + lane] = (rv && c1 < W_) ? v1 : 0.f;
            }
        }

        // MFMA
        f32x4 acc[4][4];
        #pragma unroll
        for (int tm = 0; tm < 4; ++tm)
            #pragma unroll
            for (int pn = 0; pn < 4; ++pn) acc[tm][pn] = (f32x4)(0.f);
        #pragma unroll
        for (int ks = 0; ks < 2; ++ks)
            #pragma unroll
            for (int tm = 0; tm < 4; ++tm)
                #pragma unroll
                for (int pn = 0; pn < 4; ++pn)
                    acc[tm][pn] = __builtin_amdgcn_mfma_f32_16x16x32_bf16(
                        ka[ks][tm], hb[ks][pn], acc[tm][pn], 0, 0, 0);

        // bias (zero-padded to 64 taps)
        #pragma unroll
        for (int tm = 0; tm < 4; ++tm) {
            f32x4 kv = *(const f32x4*)(kbp + g * 64 + tm * 16 + l4 * 4);
            #pragma unroll
            for (int pn = 0; pn < 4; ++pn)
                #pragma unroll
                for (int r = 0; r < 4; ++r) acc[tm][pn][r] += kv[r];
        }

        // per-px mean & inv-norm over the 49 valid taps
        float mean[4], inv[4];
        #pragma unroll
        for (int pn = 0; pn < 4; ++pn) {
            float s = 0.f;
            #pragma unroll
            for (int tm = 0; tm < 3; ++tm)
                #pragma unroll
                for (int r = 0; r < 4; ++r) s += acc[tm][pn][r];
            s += (l4 == 0) ? acc[3][pn][0] : 0.f;
            s += __shfl_xor(s, 16);
            s += __shfl_xor(s, 32);
            float m = s * (1.f / 49.f);
            float ss = 0.f;
            #pragma unroll
            for (int tm = 0; tm < 3; ++tm)
                #pragma unroll
                for (int r = 0; r < 4; ++r) {
                    float d = acc[tm][pn][r] - m;
                    ss = fmaf(d, d, ss);
                }
            float d3 = acc[3][pn][0] - m;
            ss += (l4 == 0) ? d3 * d3 : 0.f;
            ss += __shfl_xor(ss, 16);
            ss += __shfl_xor(ss, 32);
            mean[pn] = m;
            inv[pn]  = 1.f / fmaxf(sqrtf(ss), 1e-6f);
        }

        // involution: out = (sum ker*x - mean*sum x) * inv
        float kx[4] = {0.f, 0.f, 0.f, 0.f};
        float xs[4] = {0.f, 0.f, 0.f, 0.f};
        #pragma unroll
        for (int tm = 0; tm < 3; ++tm)
            #pragma unroll
            for (int r = 0; r < 4; ++r) {
                const float* base = &x_s[wave][0][0] + offs[tm][r] + l15;
                #pragma unroll
                for (int pn = 0; pn < 4; ++pn) {
                    float xv = base[pn * 16];
                    kx[pn] = fmaf(acc[tm][pn][r], xv, kx[pn]);
                    xs[pn] += xv;
                }
            }
        {   // t = 48 (i=6, j=6): valid only on l4==0 lanes
            const float* base = &x_s[wave][6][6] + l15;
            #pragma unroll
            for (int pn = 0; pn < 4; ++pn) {
                float xv = base[pn * 16];
                float kr = (l4 == 0) ? acc[3][pn][0] : 0.f;
                kx[pn] = fmaf(kr, xv, kx[pn]);
                xs[pn] += (l4 == 0) ? xv : 0.f;
            }
        }
        float ov[4];
        #pragma unroll
        for (int pn = 0; pn < 4; ++pn) {
            float k2 = kx[pn];
            k2 += __shfl_xor(k2, 16);
            k2 += __shfl_xor(k2, 32);
            float x2 = xs[pn];
            x2 += __shfl_xor(x2, 16);
            x2 += __shfl_xor(x2, 32);
            ov[pn] = (k2 - mean[pn] * x2) * inv[pn];
        }
        float outv = (l4 == 0) ? ov[0] : (l4 == 1) ? ov[1] : (l4 == 2) ? ov[2] : ov[3];
        out[((size_t)(b * G_ + g)) * HW_ + y * W_ + lane] = outv;
    }
}

// --------------------------------------------- tier-2 hv (single-stage) ----
__global__ __launch_bounds__(256) void hv_kernel(
    const float* __restrict__ x, const float* __restrict__ rwT,
    const float* __restrict__ betp, ushort* __restrict__ hv)
{
    const int lane = threadIdx.x & 63;
    const int q    = __builtin_amdgcn_readfirstlane(threadIdx.x >> 6);
    const int p    = blockIdx.x * 64 + lane;
    const int b    = p >> 12;
    const int hw   = p & 4095;
    float acc[16];
    #pragma unroll
    for (int j = 0; j < 16; ++j) acc[j] = betp[q * 16 + j];
    const float* xp = x + (size_t)b * C_ * HW_ + hw;
    #pragma unroll 8
    for (int k = 0; k < C_; ++k) {
        float xk = xp[(size_t)k * HW_];
        const float* rw = rwT + k * HID_ + q * 16;
        #pragma unroll
        for (int j = 0; j < 16; ++j) acc[j] = fmaf(xk, rw[j], acc[j]);
    }
    union { ushort s[16]; uint4 v[2]; } u;
    #pragma unroll
    for (int j = 0; j < 16; ++j) u.s[j] = f2bf(fmaxf(acc[j], 0.f));
    uint4* dst = (uint4*)(hv + (size_t)p * HID_ + q * 16);
    dst[0] = u.v[0];
    dst[1] = u.v[1];
}

// ---------------------------------------------------- fallback (no ws) ----
__global__ __launch_bounds__(256) void invol_fallback(
    const float* __restrict__ x, const float* __restrict__ reduce_w,
    const float* __restrict__ bn_gamma, const float* __restrict__ bn_beta,
    const float* __restrict__ bn_mean, const float* __restrict__ bn_var,
    const float* __restrict__ kw, const float* __restrict__ kb,
    float* __restrict__ out)
{
    __shared__ float rwT[C_][HID_ + 4];
    __shared__ float bns[HID_];
    __shared__ float bnb[HID_];
    const int tid = threadIdx.x;
    const int b  = blockIdx.z;
    const int g0 = blockIdx.y * 32;
    const int p  = blockIdx.x * 256 + tid;
    const int py = p >> 6;
    const int px = p & 63;
    #pragma unroll 1
    for (int o = 0; o < HID_; ++o) rwT[tid][o] = reduce_w[o * C_ + tid];
    if (tid < HID_) {
        float inv = bn_gamma[tid] * rsqrtf(bn_var[tid] + BN_EPS);
        bns[tid] = inv;
        bnb[tid] = bn_beta[tid] - bn_mean[tid] * inv;
    }
    __syncthreads();
    float hvv[HID_];
    #pragma unroll
    for (int o = 0; o < HID_; ++o) hvv[o] = 0.f;
    const float* xb = x + (size_t)b * C_ * HW_ + p;
    #pragma unroll 4
    for (int k = 0; k < C_; ++k) {
        float xk = xb[(size_t)k * HW_];
        const float4* wr = (const float4*)&rwT[k][0];
        #pragma unroll
        for (int o4 = 0; o4 < HID_ / 4; ++o4) {
            float4 w = wr[o4];
            hvv[o4*4+0] = fmaf(xk, w.x, hvv[o4*4+0]);
            hvv[o4*4+1] = fmaf(xk, w.y, hvv[o4*4+1]);
            hvv[o4*4+2] = fmaf(xk, w.z, hvv[o4*4+2]);
            hvv[o4*4+3] = fmaf(xk, w.w, hvv[o4*4+3]);
        }
    }
    #pragma unroll
    for (int o = 0; o < HID_; ++o) hvv[o] = fmaxf(fmaf(hvv[o], bns[o], bnb[o]), 0.f);
    #pragma unroll 1
    for (int gi = 0; gi < 32; ++gi) {
        const int g = g0 + gi;
        const float* kwg = kw + (size_t)g * KK_ * HID_;
        float acc[KK_];
        #pragma unroll
        for (int t = 0; t < KK_; ++t) {
            float a = kb[g * KK_ + t];
            const float4* row = (const float4*)(kwg + t * HID_);
            #pragma unroll
            for (int k4 = 0; k4 < HID_ / 4; ++k4) {
                float4 w = row[k4];
                a = fmaf(w.x, hvv[k4*4+0], a);
                a = fmaf(w.y, hvv[k4*4+1], a);
                a = fmaf(w.z, hvv[k4*4+2], a);
                a = fmaf(w.w, hvv[k4*4+3], a);
            }
            acc[t] = a;
        }
        float mean = 0.f;
        #pragma unroll
        for (int t = 0; t < KK_; ++t) mean += acc[t];
        mean *= (1.f / 49.f);
        float ss = 0.f;
        #pragma unroll
        for (int t = 0; t < KK_; ++t) { acc[t] -= mean; ss = fmaf(acc[t], acc[t], ss); }
        float inv = 1.f / fmaxf(sqrtf(ss), 1e-6f);
        const float* xg = x + ((size_t)(b * G_ + g)) * HW_;
        float oacc = 0.f;
        #pragma unroll
        for (int i = 0; i < KS_; ++i) {
            int yv = py + i - 3;
            bool rok = ((unsigned)yv < (unsigned)H_);
            const float* xrow = xg + yv * W_;
            #pragma unroll
            for (int j = 0; j < KS_; ++j) {
                int xx = px + j - 3;
                bool ok = rok && ((unsigned)xx < (unsigned)W_);
                float v = ok ? xrow[xx] : 0.f;
                oacc = fmaf(v, acc[i*7+j], oacc);
            }
        }
        out[((size_t)(b * G_ + g)) * HW_ + p] = oacc * inv;
    }
}

extern "C" void kernel_launch(void* const* d_in, const int* in_sizes, int n_in,
                              void* d_out, int out_size, void* d_ws, size_t ws_size,
                              hipStream_t stream) {
    const float* x        = (const float*)d_in[0];
    const float* reduce_w = (const float*)d_in[1];
    const float* bn_gamma = (const float*)d_in[2];
    const float* bn_beta  = (const float*)d_in[3];
    const float* bn_mean  = (const float*)d_in[4];
    const float* bn_var   = (const float*)d_in[5];
    const float* kproj_w  = (const float*)d_in[6];
    const float* kproj_b  = (const float*)d_in[7];
    float* out = (float*)d_out;
    const int B   = in_sizes[0] / (C_ * HW_);
    const int npx = B * HW_;

    size_t kwb_off = 0;
    size_t kwb_sz  = (size_t)G_ * 64 * 64 * 2;        // 2 MB
    size_t kbp_off = kwb_off + kwb_sz;
    size_t kbp_sz  = (size_t)G_ * 64 * 4;             // 64 KB
    size_t rwt_off = kbp_off + kbp_sz;
    size_t rwt_sz  = (size_t)C_ * HID_ * 4;           // 64 KB
    size_t bet_off = rwt_off + rwt_sz;
    size_t bet_sz  = 256;
    size_t hv_off  = bet_off + bet_sz;
    size_t hv_sz   = (size_t)npx * HID_ * 2;          // 2 MB
    size_t hvp_off = hv_off + hv_sz;
    size_t hvp_sz  = (size_t)4 * HID_ * npx * 4;      // 16 MB
    size_t need2   = hvp_off;                          // without hvp
    size_t need    = hvp_off + hvp_sz;

    if (ws_size < need2) {
        dim3 grid(HW_ / 256, G_ / 32, B);
        invol_fallback<<<grid, 256, 0, stream>>>(x, reduce_w, bn_gamma, bn_beta,
                                                 bn_mean, bn_var, kproj_w, kproj_b, out);
        return;
    }

    ushort* kwb  = (ushort*)((char*)d_ws + kwb_off);
    float*  kbp  = (float*)((char*)d_ws + kbp_off);
    float*  rwT  = (float*)((char*)d_ws + rwt_off);
    float*  betp = (float*)((char*)d_ws + bet_off);
    ushort* hv   = (ushort*)((char*)d_ws + hv_off);
    float*  hvp  = (float*)((char*)d_ws + hvp_off);

    prep_kernel<<<dim3(258), 256, 0, stream>>>(kproj_w, kproj_b, reduce_w,
                                               bn_gamma, bn_beta, bn_mean, bn_var,
                                               kwb, rwT, betp, kbp);
    if (ws_size >= need) {
        hv1_kernel<<<dim3(npx / 64, 4), 256, 0, stream>>>(x, rwT, hvp, npx);
        hv2_kernel<<<dim3(npx / 256, 16), 256, 0, stream>>>(hvp, betp, hv, npx);
    } else {
        hv_kernel<<<dim3(npx / 64), 256, 0, stream>>>(x, rwT, betp, hv);
    }
    invol_main<<<dim3(B * H_, 16), 256, 0, stream>>>(x, hv, kwb, kbp, out);
}